// Round 6
// baseline (196.023 us; speedup 1.0000x reference)
//
#include <hip/hip_runtime.h>
#include <hip/hip_bf16.h>

#define EMBED 256
#define NH 8
#define NL 4
#define NP 4
#define HD 32
#define BS 4
#define NQ 4000
#define NV 13294

using f32x4   = __attribute__((ext_vector_type(4))) float;
using bf16x8  = __attribute__((ext_vector_type(8))) short;

__device__ __forceinline__ float bf2f_lo(unsigned u) {
    union { unsigned u; float f; } x; x.u = u << 16; return x.f;
}
__device__ __forceinline__ float bf2f_hi(unsigned u) {
    union { unsigned u; float f; } x; x.u = u & 0xffff0000u; return x.f;
}
__device__ __forceinline__ unsigned short f2bf(float f) {
    union { float f; unsigned u; } x; x.f = f;
    unsigned u = x.u;
    return (unsigned short)((u + 0x7fffu + ((u >> 16) & 1u)) >> 16);
}
// packed f32->bf16 RNE, 2 elems/instr
__device__ __forceinline__ unsigned cvtpk(float lo, float hi) {
    unsigned r;
    asm("v_cvt_pk_bf16_f32 %0, %1, %2" : "=v"(r) : "v"(lo), "v"(hi));
    return r;
}

// async 16B/lane global->LDS DMA. LDS dest wave-uniform base; lane i at base+i*16.
__device__ __forceinline__ void async16(const void* g, void* l) {
    __builtin_amdgcn_global_load_lds(
        (const __attribute__((address_space(1))) void*)g,
        (__attribute__((address_space(3))) void*)l, 16, 0, 0);
}

template<int N> __device__ __forceinline__ void wait_vmcnt() {
    if constexpr (N == 0)      asm volatile("s_waitcnt vmcnt(0)" ::: "memory");
    else if constexpr (N == 2) asm volatile("s_waitcnt vmcnt(2)" ::: "memory");
    else if constexpr (N == 3) asm volatile("s_waitcnt vmcnt(3)" ::: "memory");
}

// ---------- prep: weight transposes + bias concat only ----------
__global__ __launch_bounds__(256) void msda_prep_k(
    const float* __restrict__ W_val, const float* __restrict__ W_out,
    const float* __restrict__ W_off, const float* __restrict__ W_attn,
    const float* __restrict__ b_off, const float* __restrict__ b_attn,
    unsigned short* __restrict__ Wt_val, unsigned short* __restrict__ Wt_out,
    unsigned short* __restrict__ Wt_qa, float* __restrict__ b_qa)
{
    int i = blockIdx.x * 256 + threadIdx.x;      // 896 blocks -> 229,376 elems
    if (i < 384) b_qa[i] = (i < 256) ? b_off[i] : b_attn[i - 256];
    if (i < 65536) {
        int r = i >> 8, c = i & 255;
        Wt_val[c * 256 + r] = f2bf(W_val[i]);
    } else if (i < 131072) {
        int j = i - 65536, r = j >> 8, c = j & 255;
        Wt_out[c * 256 + r] = f2bf(W_out[j]);
    } else if (i < 229376) {
        int j = i - 131072;              // j = n*256 + k, n in [0,384)
        int n = j >> 8, k = j & 255;
        float v = (n < 256) ? W_off[k * 256 + n] : W_attn[k * 128 + (n - 256)];
        Wt_qa[j] = f2bf(v);
    }
}

// ---------- GEMM body: 8-wave 128x128 tile, triple-buffered counted-vmcnt ----------
// 512 threads = 8 waves; wave w owns sub-tile (wm=(w&1)*64, wn=(w>>1)*32), NI=2.
// Buffer = A[128][32]bf16 (8KB) + B[128][32]bf16 (8KB) = 16KB; x3 = 48KB
//   -> 3 blocks/CU x 8 waves = 24 waves/CU (75% occupancy bound, vs 16 at R5).
// A staging (T14): global (fp32 or bf16) -> regs (1 iter early, parity reg-sets)
//   -> cvt_pk -> ds_write_b128.  B staging: 1 global_load_lds DMA / wave / chunk.
// vmcnt discipline (in-order drain, oldest-first):
//   per wave per chunk vmem = LOPS A-loads + 1 B-DMA.  At top of iter c the only
//   ops possibly newer than B(c) are A(c+1)[LOPS] + B(c+1)[1]  (A(c) was drained
//   by writeA(c)'s register dependency in iter c-1, compiler-inserted exact wait).
//   So wait vmcnt(LOPS+1) guarantees B(c) landed.  sched_barrier(0) at iter top
//   fences cross-iteration motion, making the count robust to scheduling.
// EPI 0: bf16 out in [b][h][pix][32ch] layout via LDS bounce (v_buf for sampler).
// EPI 1: fp32 row-major [M][N] direct.
template<int EPI, bool ABF16>
__device__ __forceinline__ void gemm_body(
    char* lds,
    const void* __restrict__ Ap,
    const unsigned short* __restrict__ Bt,
    const float* __restrict__ bias,
    void* __restrict__ out,
    int M, int N, int mblk, int nblk)
{
    constexpr int K = 256, C = 8;
    constexpr int NI = 2;
    constexpr int ABYTES = 128 * 32 * 2;         // 8192 (A always bf16 in LDS)
    constexpr int BUFB   = ABYTES + 128 * 32 * 2;// 16384
    constexpr int LOPS   = ABF16 ? 1 : 2;        // A global loads / lane / chunk

    const int m0 = mblk * 128, n0 = nblk * 128;
    const int tid  = threadIdx.x;
    const int w    = tid >> 6;
    const int lane = tid & 63;
    const int quad = lane >> 4;
    const int l16  = lane & 15;
    const int wm   = (w & 1) * 64;
    const int wn   = (w >> 1) * 32;

    // ---- A reg-stage mapping: row = tid>>2 (0..127), k-elems (tid&3)*8..+8 ----
    const int ar  = tid >> 2;
    const int arg = min(m0 + ar, M - 1);
    const int ak  = (tid & 3) * 8;
    const float*          afp = (const float*)Ap          + (size_t)arg * K + ak;
    const unsigned short* abp = (const unsigned short*)Ap + (size_t)arg * K + ak;

    // ---- B DMA: 1 instr/wave/chunk; wave w stages rows w*16..+15 (1KB linear) ----
    const char* bgp = (const char*)(Bt + (size_t)(n0 + w * 16 + (lane >> 2)) * K)
                      + (lane & 3) * 16;

    auto issueB = [&](int c, int kb) {
        async16(bgp + c * 64, lds + kb * BUFB + ABYTES + w * 1024);
    };

    float4 aLoR[2], aHiR[2];                     // parity reg-sets (unroll folds idx)
    bf16x8 aRegR[2];
    auto loadA = [&](int c) {
        const int p = c & 1;
        if constexpr (ABF16) {
            aRegR[p] = *(const bf16x8*)(abp + c * 32);
        } else {
            aLoR[p] = *(const float4*)(afp + c * 32);
            aHiR[p] = *(const float4*)(afp + c * 32 + 4);
        }
    };
    auto writeA = [&](int c) {
        const int p = c & 1;
        unsigned short* dst = (unsigned short*)(lds + (c % 3) * BUFB) + ar * 32 + ak;
        if constexpr (ABF16) {
            *(bf16x8*)dst = aRegR[p];
        } else {
            union { unsigned u[4]; bf16x8 v; } t;
            t.u[0] = cvtpk(aLoR[p].x, aLoR[p].y); t.u[1] = cvtpk(aLoR[p].z, aLoR[p].w);
            t.u[2] = cvtpk(aHiR[p].x, aHiR[p].y); t.u[3] = cvtpk(aHiR[p].z, aHiR[p].w);
            *(bf16x8*)dst = t.v;
        }
    };

    f32x4 acc[4][NI];
#pragma unroll
    for (int a = 0; a < 4; a++)
#pragma unroll
        for (int b = 0; b < NI; b++) acc[a][b] = (f32x4){0.f, 0.f, 0.f, 0.f};

    // prologue: L(0), B(0), L(1), B(1); writeA(0) (compiler waits L(0) regs)
    loadA(0); issueB(0, 0); loadA(1); issueB(1, 1);
    writeA(0);

#pragma unroll
    for (int c = 0; c < C; c++) {
        if (c < C - 1) wait_vmcnt<LOPS + 1>(); else wait_vmcnt<0>();
        asm volatile("s_waitcnt lgkmcnt(0)" ::: "memory");   // my A ds_writes visible
        __builtin_amdgcn_s_barrier();                        // buf c%3 fully valid
        __builtin_amdgcn_sched_barrier(0);                   // iteration fence
        if (c + 2 < C) { loadA(c + 2); issueB(c + 2, (c + 2) % 3); }

        const char* aL = lds + (c % 3) * BUFB;
        const char* bL = aL + ABYTES;
        bf16x8 af[4], bfr[NI];
#pragma unroll
        for (int mi = 0; mi < 4; mi++)
            af[mi] = *(const bf16x8*)(aL + (wm + mi * 16 + l16) * 64 + quad * 16);
#pragma unroll
        for (int ni = 0; ni < NI; ni++)
            bfr[ni] = *(const bf16x8*)(bL + (wn + ni * 16 + l16) * 64 + quad * 16);

        if (c + 1 < C) writeA(c + 1);            // buf (c+1)%3 last read iter c-2: safe

#pragma unroll
        for (int mi = 0; mi < 4; mi++)
#pragma unroll
            for (int ni = 0; ni < NI; ni++)
                acc[mi][ni] = __builtin_amdgcn_mfma_f32_16x16x32_bf16(af[mi], bfr[ni], acc[mi][ni], 0, 0, 0);
    }

    if constexpr (EPI == 0) {
        // bounce -> v_buf in [b][h][pix][32ch] bf16 layout (sampler-friendly:
        // x-adjacent bilinear corners 64B apart -> share cachelines)
        __syncthreads();                          // cs overlaps pipeline buffers
        unsigned short* cs = (unsigned short*)lds;   // [128][136] = 34816B < 48KB
#pragma unroll
        for (int ni = 0; ni < NI; ni++) {
            int cl = wn + ni * 16 + l16;
            float bvv = bias[n0 + cl];
#pragma unroll
            for (int mi = 0; mi < 4; mi++)
#pragma unroll
                for (int r = 0; r < 4; r++) {
                    int ml = wm + mi * 16 + quad * 4 + r;
                    cs[ml * 136 + cl] = f2bf(acc[mi][ni][r] + bvv);
                }
        }
        __syncthreads();
        // writer: seg = head index (tid>>7), rr = pixel row (tid&127);
        // each thread stores one 64B head-row as 4 x 16B.
        const int seg = tid >> 7, rr = tid & 127;
        const int m = m0 + rr;
        if (m < M) {
            const int b   = m / NV;
            const int pix = m - b * NV;
            const int h   = (n0 >> 5) + seg;
            char* dst = (char*)out + (((size_t)b * 8 + h) * NV + pix) * 64;
            const uint4* s = (const uint4*)&cs[rr * 136 + seg * 32];
#pragma unroll
            for (int j = 0; j < 4; j++) ((uint4*)dst)[j] = s[j];
        }
    } else {
#pragma unroll
        for (int ni = 0; ni < NI; ni++) {
            int cc = n0 + wn + ni * 16 + l16;
            float bvv = bias[cc];
#pragma unroll
            for (int mi = 0; mi < 4; mi++)
#pragma unroll
                for (int r = 0; r < 4; r++) {
                    int m = m0 + wm + mi * 16 + quad * 4 + r;
                    if (m >= M) continue;
                    ((float*)out)[(size_t)m * N + cc] = acc[mi][ni][r] + bvv;
                }
        }
    }
}

// ---------- merged value-GEMM + qa-GEMM ----------
// value: 416 m-tiles x 2 n = 832 blocks (EPI0, A fp32)
// qa:    125 m-tiles x 3 n = 375 blocks (EPI1, A fp32)
__global__ __launch_bounds__(512) void msda_gemm_vq_k(
    const float* __restrict__ value, const float* __restrict__ query,
    const unsigned short* __restrict__ Wt_val, const unsigned short* __restrict__ Wt_qa,
    const float* __restrict__ b_val, const float* __restrict__ b_qa,
    unsigned short* __restrict__ v_buf, float* __restrict__ oa_buf)
{
    extern __shared__ char lds[];
    const int bx = blockIdx.x;
    if (bx < 832) {
        gemm_body<0, false>(lds, value, Wt_val, b_val, v_buf,
                            BS * NV, 256, bx >> 1, bx & 1);
    } else {
        const int j = bx - 832;
        const int mb = j / 3;
        gemm_body<1, false>(lds, query, Wt_qa, b_qa, oa_buf,
                            BS * NQ, 384, mb, j - mb * 3);
    }
}

// ---------- out GEMM (after sampler): A bf16 reg-staged ----------
__global__ __launch_bounds__(512) void msda_gemm_out_k(
    const unsigned short* __restrict__ t_buf,
    const unsigned short* __restrict__ Wt_out,
    const float* __restrict__ b_out,
    float* __restrict__ out)
{
    extern __shared__ char lds[];
    const int bx = blockIdx.x;
    gemm_body<1, true>(lds, t_buf, Wt_out, b_out, out,
                       BS * NQ, 256, bx >> 1, bx & 1);
}

// ---------- sampler: 4 queries/block, wave = 1 query, thread = (h, 4-chan grp) ----------
// v_buf layout: [b][h][pix][32ch] bf16 (64B per (b,h,pix) row)
__global__ __launch_bounds__(256) void msda_sampler_k(
    const float* __restrict__ refpts,            // (BS*NQ, 8) fp32
    const float* __restrict__ oa_buf,            // (BS*NQ, 384) fp32: off[256] | attn[128]
    const unsigned short* __restrict__ v_buf,    // [BS][NH][NV][32] bf16
    unsigned short* __restrict__ t_out)          // (BS*NQ, 256) bf16
{
    __shared__ float  oa_s[4][384];
    __shared__ float  ref_s[4][8];
    __shared__ float4 wtab[528];                 // idx = i*33 + ql*8 + h (stride-33 pad)
    __shared__ int4   itab[528];

    const int tid = threadIdx.x;
    const int q0  = blockIdx.x * 4;

    // phase 1: cooperative loads
    {
        const float4* src = (const float4*)(oa_buf + (size_t)q0 * 384);
        float4* dst = (float4*)&oa_s[0][0];
        dst[tid] = src[tid];
        if (tid < 128) dst[256 + tid] = src[256 + tid];
        if (tid < 32) ((float*)ref_s)[tid] = refpts[q0 * 8 + tid];
    }
    __syncthreads();

    // phase 2+3 fused: shuffle softmax (16 lanes = one (q,h) group) + tables
    const int HWs[4]    = {100, 50, 25, 13};
    const int starts[4] = {0, 10000, 12500, 13125};
#pragma unroll
    for (int it = 0; it < 2; it++) {
        int s  = tid + it * 256;                 // 0..511
        int i  = s & 15;                         // l*4+p
        int h  = (s >> 4) & 7;
        int ql = s >> 7;
        int l  = i >> 2, p = i & 3;
        float logit = oa_s[ql][256 + h * 16 + i];
        float m = logit;
#pragma unroll
        for (int off = 1; off < 16; off <<= 1) m = fmaxf(m, __shfl_xor(m, off, 64));
        float e = __expf(logit - m);
        float sum = e;
#pragma unroll
        for (int off = 1; off < 16; off <<= 1) sum += __shfl_xor(sum, off, 64);
        float a = e / sum;

        int Wl = HWs[l];
        float fW = (float)Wl;
        float rx = ref_s[ql][l * 2], ry = ref_s[ql][l * 2 + 1];
        float offx = oa_s[ql][h * 32 + l * 8 + p * 2];
        float offy = oa_s[ql][h * 32 + l * 8 + p * 2 + 1];
        float x = rx * fW + offx - 0.5f;
        float y = ry * fW + offy - 0.5f;
        float xf = floorf(x), yf = floorf(y);
        float fx = x - xf, fy = y - yf;
        int x0 = (int)xf, y0 = (int)yf;
        int x1 = x0 + 1, y1 = y0 + 1;
        float wx0 = (x0 >= 0 && x0 < Wl) ? (1.f - fx) : 0.f;
        float wx1 = (x1 >= 0 && x1 < Wl) ? fx : 0.f;
        float wy0 = (y0 >= 0 && y0 < Wl) ? (1.f - fy) : 0.f;
        float wy1 = (y1 >= 0 && y1 < Wl) ? fy : 0.f;
        int x0c = min(max(x0, 0), Wl - 1), x1c = min(max(x1, 0), Wl - 1);
        int y0c = min(max(y0, 0), Wl - 1), y1c = min(max(y1, 0), Wl - 1);
        int r0 = starts[l] + y0c * Wl, r1 = starts[l] + y1c * Wl;
        int ti = i * 33 + ql * 8 + h;
        wtab[ti] = make_float4(wx0 * wy0 * a, wx1 * wy0 * a, wx0 * wy1 * a, wx1 * wy1 * a);
        itab[ti] = make_int4(r0 + x0c, r0 + x1c, r1 + x0c, r1 + x1c);
    }
    __syncthreads();

    // phase 4: gather + weighted accumulate, 4 channels per thread
    const int dg = tid & 7, h = (tid >> 3) & 7, ql = tid >> 6;
    const int q = q0 + ql;
    const int b = q / NQ;
    const char* base = (const char*)v_buf + ((size_t)(b * 8 + h)) * NV * 64 + dg * 8;
    const int tbase = ql * 8 + h;

    float a0 = 0.f, a1 = 0.f, a2 = 0.f, a3 = 0.f;
#pragma unroll
    for (int lp = 0; lp < 16; lp++) {
        float4 wv = wtab[lp * 33 + tbase];
        int4   ix = itab[lp * 33 + tbase];
        uint2 s0 = *(const uint2*)(base + ((unsigned)ix.x << 6));
        uint2 s1 = *(const uint2*)(base + ((unsigned)ix.y << 6));
        uint2 s2 = *(const uint2*)(base + ((unsigned)ix.z << 6));
        uint2 s3 = *(const uint2*)(base + ((unsigned)ix.w << 6));
        a0 += wv.x * bf2f_lo(s0.x); a1 += wv.x * bf2f_hi(s0.x);
        a2 += wv.x * bf2f_lo(s0.y); a3 += wv.x * bf2f_hi(s0.y);
        a0 += wv.y * bf2f_lo(s1.x); a1 += wv.y * bf2f_hi(s1.x);
        a2 += wv.y * bf2f_lo(s1.y); a3 += wv.y * bf2f_hi(s1.y);
        a0 += wv.z * bf2f_lo(s2.x); a1 += wv.z * bf2f_hi(s2.x);
        a2 += wv.z * bf2f_lo(s2.y); a3 += wv.z * bf2f_hi(s2.y);
        a0 += wv.w * bf2f_lo(s3.x); a1 += wv.w * bf2f_hi(s3.x);
        a2 += wv.w * bf2f_lo(s3.y); a3 += wv.w * bf2f_hi(s3.y);
    }
    unsigned o0 = (unsigned)f2bf(a0) | ((unsigned)f2bf(a1) << 16);
    unsigned o1 = (unsigned)f2bf(a2) | ((unsigned)f2bf(a3) << 16);
    uint2 o = {o0, o1};
    *(uint2*)(t_out + (size_t)q * 256 + h * 32 + dg * 4) = o;
}

extern "C" void kernel_launch(void* const* d_in, const int* in_sizes, int n_in,
                              void* d_out, int out_size, void* d_ws, size_t ws_size,
                              hipStream_t stream) {
    const float* query  = (const float*)d_in[0];
    const float* value  = (const float*)d_in[1];
    const float* refpts = (const float*)d_in[2];
    // d_in[3] = spatial_shapes (int32) — fixed {100,50,25,13}^2, hard-coded.
    const float* W_off  = (const float*)d_in[4];
    const float* b_off  = (const float*)d_in[5];
    const float* W_attn = (const float*)d_in[6];
    const float* b_attn = (const float*)d_in[7];
    const float* W_val  = (const float*)d_in[8];
    const float* b_val  = (const float*)d_in[9];
    const float* W_out  = (const float*)d_in[10];
    const float* b_out  = (const float*)d_in[11];

    char* wsp = (char*)d_ws;
    size_t o = 0;
    auto carve = [&](size_t bytes) -> void* {
        void* p = wsp + o; o += (bytes + 255) & ~(size_t)255; return p;
    };
    unsigned short* Wt_val = (unsigned short*)carve(256 * 256 * 2);
    unsigned short* Wt_out = (unsigned short*)carve(256 * 256 * 2);
    unsigned short* Wt_qa  = (unsigned short*)carve(384 * 256 * 2);
    float*          b_qa   = (float*)carve(384 * 4);
    unsigned short* v_buf  = (unsigned short*)carve((size_t)BS * NH * NV * 32 * 2);
    float*          oa_buf = (float*)carve((size_t)BS * NQ * 384 * 4);
    unsigned short* t_buf  = (unsigned short*)carve((size_t)BS * NQ * EMBED * 2);

    msda_prep_k<<<896, 256, 0, stream>>>(W_val, W_out, W_off, W_attn,
                                         b_off, b_attn, Wt_val, Wt_out, Wt_qa, b_qa);

    // merged: 832 value blocks + 375 qa blocks; 512 thr, 3x16KB LDS -> 3 blk/CU (24 waves)
    msda_gemm_vq_k<<<832 + 375, 512, 49152, stream>>>(value, query, Wt_val, Wt_qa,
                                                      b_val, b_qa, v_buf, oa_buf);
    // sampler reads oa_buf + v_buf([b][h][pix][32]), writes t_buf
    msda_sampler_k<<<(BS * NQ) / 4, 256, 0, stream>>>(refpts, oa_buf, v_buf, t_buf);
    // out GEMM: 125 m-tiles x 2 n-tiles, reg-staged bf16 A
    msda_gemm_out_k<<<250, 512, 49152, stream>>>(t_buf, Wt_out, b_out, (float*)d_out);
}

// Round 7
// 193.622 us; speedup vs baseline: 1.0124x; 1.0124x over previous
//
#include <hip/hip_runtime.h>
#include <hip/hip_bf16.h>

#define EMBED 256
#define NH 8
#define NL 4
#define NP 4
#define HD 32
#define BS 4
#define NQ 4000
#define NV 13294

using f32x4   = __attribute__((ext_vector_type(4))) float;
using bf16x8  = __attribute__((ext_vector_type(8))) short;

__device__ __forceinline__ float bf2f_lo(unsigned u) {
    union { unsigned u; float f; } x; x.u = u << 16; return x.f;
}
__device__ __forceinline__ float bf2f_hi(unsigned u) {
    union { unsigned u; float f; } x; x.u = u & 0xffff0000u; return x.f;
}
__device__ __forceinline__ unsigned short f2bf(float f) {
    union { float f; unsigned u; } x; x.f = f;
    unsigned u = x.u;
    return (unsigned short)((u + 0x7fffu + ((u >> 16) & 1u)) >> 16);
}
// packed f32->bf16 RNE, 2 elems/instr
__device__ __forceinline__ unsigned cvtpk(float lo, float hi) {
    unsigned r;
    asm("v_cvt_pk_bf16_f32 %0, %1, %2" : "=v"(r) : "v"(lo), "v"(hi));
    return r;
}

// async 16B/lane global->LDS DMA. LDS dest wave-uniform base; lane i at base+i*16.
__device__ __forceinline__ void async16(const void* g, void* l) {
    __builtin_amdgcn_global_load_lds(
        (const __attribute__((address_space(1))) void*)g,
        (__attribute__((address_space(3))) void*)l, 16, 0, 0);
}

template<int N> __device__ __forceinline__ void wait_vmcnt() {
    if constexpr (N == 0)      asm volatile("s_waitcnt vmcnt(0)" ::: "memory");
    else if constexpr (N == 2) asm volatile("s_waitcnt vmcnt(2)" ::: "memory");
    else if constexpr (N == 3) asm volatile("s_waitcnt vmcnt(3)" ::: "memory");
}

// ---------- prep: weight transposes + bias concat only ----------
__global__ __launch_bounds__(256) void msda_prep_k(
    const float* __restrict__ W_val, const float* __restrict__ W_out,
    const float* __restrict__ W_off, const float* __restrict__ W_attn,
    const float* __restrict__ b_off, const float* __restrict__ b_attn,
    unsigned short* __restrict__ Wt_val, unsigned short* __restrict__ Wt_out,
    unsigned short* __restrict__ Wt_qa, float* __restrict__ b_qa)
{
    int i = blockIdx.x * 256 + threadIdx.x;      // 896 blocks -> 229,376 elems
    if (i < 384) b_qa[i] = (i < 256) ? b_off[i] : b_attn[i - 256];
    if (i < 65536) {
        int r = i >> 8, c = i & 255;
        Wt_val[c * 256 + r] = f2bf(W_val[i]);
    } else if (i < 131072) {
        int j = i - 65536, r = j >> 8, c = j & 255;
        Wt_out[c * 256 + r] = f2bf(W_out[j]);
    } else if (i < 229376) {
        int j = i - 131072;              // j = n*256 + k, n in [0,384)
        int n = j >> 8, k = j & 255;
        float v = (n < 256) ? W_off[k * 256 + n] : W_attn[k * 128 + (n - 256)];
        Wt_qa[j] = f2bf(v);
    }
}

// ---------- GEMM body: 8-wave 128x128 tile, triple-buffered counted-vmcnt ----------
// (unchanged from R6 — vq measured at its mixed-R/W HBM service floor)
template<int EPI, bool ABF16>
__device__ __forceinline__ void gemm_body(
    char* lds,
    const void* __restrict__ Ap,
    const unsigned short* __restrict__ Bt,
    const float* __restrict__ bias,
    void* __restrict__ out,
    int M, int N, int mblk, int nblk)
{
    constexpr int K = 256, C = 8;
    constexpr int NI = 2;
    constexpr int ABYTES = 128 * 32 * 2;         // 8192 (A always bf16 in LDS)
    constexpr int BUFB   = ABYTES + 128 * 32 * 2;// 16384
    constexpr int LOPS   = ABF16 ? 1 : 2;        // A global loads / lane / chunk

    const int m0 = mblk * 128, n0 = nblk * 128;
    const int tid  = threadIdx.x;
    const int w    = tid >> 6;
    const int lane = tid & 63;
    const int quad = lane >> 4;
    const int l16  = lane & 15;
    const int wm   = (w & 1) * 64;
    const int wn   = (w >> 1) * 32;

    // ---- A reg-stage mapping: row = tid>>2 (0..127), k-elems (tid&3)*8..+8 ----
    const int ar  = tid >> 2;
    const int arg = min(m0 + ar, M - 1);
    const int ak  = (tid & 3) * 8;
    const float*          afp = (const float*)Ap          + (size_t)arg * K + ak;
    const unsigned short* abp = (const unsigned short*)Ap + (size_t)arg * K + ak;

    // ---- B DMA: 1 instr/wave/chunk; wave w stages rows w*16..+15 (1KB linear) ----
    const char* bgp = (const char*)(Bt + (size_t)(n0 + w * 16 + (lane >> 2)) * K)
                      + (lane & 3) * 16;

    auto issueB = [&](int c, int kb) {
        async16(bgp + c * 64, lds + kb * BUFB + ABYTES + w * 1024);
    };

    float4 aLoR[2], aHiR[2];                     // parity reg-sets (unroll folds idx)
    bf16x8 aRegR[2];
    auto loadA = [&](int c) {
        const int p = c & 1;
        if constexpr (ABF16) {
            aRegR[p] = *(const bf16x8*)(abp + c * 32);
        } else {
            aLoR[p] = *(const float4*)(afp + c * 32);
            aHiR[p] = *(const float4*)(afp + c * 32 + 4);
        }
    };
    auto writeA = [&](int c) {
        const int p = c & 1;
        unsigned short* dst = (unsigned short*)(lds + (c % 3) * BUFB) + ar * 32 + ak;
        if constexpr (ABF16) {
            *(bf16x8*)dst = aRegR[p];
        } else {
            union { unsigned u[4]; bf16x8 v; } t;
            t.u[0] = cvtpk(aLoR[p].x, aLoR[p].y); t.u[1] = cvtpk(aLoR[p].z, aLoR[p].w);
            t.u[2] = cvtpk(aHiR[p].x, aHiR[p].y); t.u[3] = cvtpk(aHiR[p].z, aHiR[p].w);
            *(bf16x8*)dst = t.v;
        }
    };

    f32x4 acc[4][NI];
#pragma unroll
    for (int a = 0; a < 4; a++)
#pragma unroll
        for (int b = 0; b < NI; b++) acc[a][b] = (f32x4){0.f, 0.f, 0.f, 0.f};

    // prologue: L(0), B(0), L(1), B(1); writeA(0) (compiler waits L(0) regs)
    loadA(0); issueB(0, 0); loadA(1); issueB(1, 1);
    writeA(0);

#pragma unroll
    for (int c = 0; c < C; c++) {
        if (c < C - 1) wait_vmcnt<LOPS + 1>(); else wait_vmcnt<0>();
        asm volatile("s_waitcnt lgkmcnt(0)" ::: "memory");   // my A ds_writes visible
        __builtin_amdgcn_s_barrier();                        // buf c%3 fully valid
        __builtin_amdgcn_sched_barrier(0);                   // iteration fence
        if (c + 2 < C) { loadA(c + 2); issueB(c + 2, (c + 2) % 3); }

        const char* aL = lds + (c % 3) * BUFB;
        const char* bL = aL + ABYTES;
        bf16x8 af[4], bfr[NI];
#pragma unroll
        for (int mi = 0; mi < 4; mi++)
            af[mi] = *(const bf16x8*)(aL + (wm + mi * 16 + l16) * 64 + quad * 16);
#pragma unroll
        for (int ni = 0; ni < NI; ni++)
            bfr[ni] = *(const bf16x8*)(bL + (wn + ni * 16 + l16) * 64 + quad * 16);

        if (c + 1 < C) writeA(c + 1);            // buf (c+1)%3 last read iter c-2: safe

#pragma unroll
        for (int mi = 0; mi < 4; mi++)
#pragma unroll
            for (int ni = 0; ni < NI; ni++)
                acc[mi][ni] = __builtin_amdgcn_mfma_f32_16x16x32_bf16(af[mi], bfr[ni], acc[mi][ni], 0, 0, 0);
    }

    if constexpr (EPI == 0) {
        // bounce -> v_buf in [b][h][pix][32ch] bf16 layout
        __syncthreads();                          // cs overlaps pipeline buffers
        unsigned short* cs = (unsigned short*)lds;   // [128][136] = 34816B < 48KB
#pragma unroll
        for (int ni = 0; ni < NI; ni++) {
            int cl = wn + ni * 16 + l16;
            float bvv = bias[n0 + cl];
#pragma unroll
            for (int mi = 0; mi < 4; mi++)
#pragma unroll
                for (int r = 0; r < 4; r++) {
                    int ml = wm + mi * 16 + quad * 4 + r;
                    cs[ml * 136 + cl] = f2bf(acc[mi][ni][r] + bvv);
                }
        }
        __syncthreads();
        const int seg = tid >> 7, rr = tid & 127;
        const int m = m0 + rr;
        if (m < M) {
            const int b   = m / NV;
            const int pix = m - b * NV;
            const int h   = (n0 >> 5) + seg;
            char* dst = (char*)out + (((size_t)b * 8 + h) * NV + pix) * 64;
            const uint4* s = (const uint4*)&cs[rr * 136 + seg * 32];
#pragma unroll
            for (int j = 0; j < 4; j++) ((uint4*)dst)[j] = s[j];
        }
    } else {
#pragma unroll
        for (int ni = 0; ni < NI; ni++) {
            int cc = n0 + wn + ni * 16 + l16;
            float bvv = bias[cc];
#pragma unroll
            for (int mi = 0; mi < 4; mi++)
#pragma unroll
                for (int r = 0; r < 4; r++) {
                    int m = m0 + wm + mi * 16 + quad * 4 + r;
                    if (m >= M) continue;
                    ((float*)out)[(size_t)m * N + cc] = acc[mi][ni][r] + bvv;
                }
        }
    }
}

// ---------- merged value-GEMM + qa-GEMM ----------
__global__ __launch_bounds__(512) void msda_gemm_vq_k(
    const float* __restrict__ value, const float* __restrict__ query,
    const unsigned short* __restrict__ Wt_val, const unsigned short* __restrict__ Wt_qa,
    const float* __restrict__ b_val, const float* __restrict__ b_qa,
    unsigned short* __restrict__ v_buf, float* __restrict__ oa_buf)
{
    extern __shared__ char lds[];
    const int bx = blockIdx.x;
    if (bx < 832) {
        gemm_body<0, false>(lds, value, Wt_val, b_val, v_buf,
                            BS * NV, 256, bx >> 1, bx & 1);
    } else {
        const int j = bx - 832;
        const int mb = j / 3;
        gemm_body<1, false>(lds, query, Wt_qa, b_qa, oa_buf,
                            BS * NQ, 384, mb, j - mb * 3);
    }
}

// ---------- out GEMM (after sampler): A bf16 reg-staged ----------
__global__ __launch_bounds__(512) void msda_gemm_out_k(
    const unsigned short* __restrict__ t_buf,
    const unsigned short* __restrict__ Wt_out,
    const float* __restrict__ b_out,
    float* __restrict__ out)
{
    extern __shared__ char lds[];
    const int bx = blockIdx.x;
    gemm_body<1, true>(lds, t_buf, Wt_out, b_out, out,
                       BS * NQ, 256, bx >> 1, bx & 1);
}

// ---------- sampler: 4 queries/block, wave = 1 query ----------
// v_buf layout: [b][h][pix][32ch] bf16 (64B per (b,h,pix) row).
// Phase 4 restructure (R7): lane = (h, xc, chgrp4).  The two x-corners of a
// bilinear tap are ADJACENT 64B rows -> a 128B contiguous span.  Each thread
// loads 16B (8 channels) from physical row xb+xc (xb = clamp(x0,0,W-2)); the
// x-weights are remapped onto physical rows (wlo/whi) in phase 3 — exactly
// equivalent incl. clamp/OOB cases because zeroed weights kill the extra
// reads.  2 gather instrs per tap instead of 4 (~25% fewer L1 transactions,
// 50% fewer load issues); one shfl_xor(,4) folds the x-split at the end.
__global__ __launch_bounds__(256) void msda_sampler_k(
    const float* __restrict__ refpts,            // (BS*NQ, 8) fp32
    const float* __restrict__ oa_buf,            // (BS*NQ, 384) fp32: off[256] | attn[128]
    const unsigned short* __restrict__ v_buf,    // [BS][NH][NV][32] bf16
    unsigned short* __restrict__ t_out)          // (BS*NQ, 256) bf16
{
    __shared__ float  oa_s[4][384];
    __shared__ float  ref_s[4][8];
    __shared__ float4 wtab[528];                 // idx = i*33 + ql*8 + h (stride-33 pad)
    __shared__ int2   itab[528];                 // (row_lo_y0, row_lo_y1)

    const int tid = threadIdx.x;
    const int q0  = blockIdx.x * 4;

    // phase 1: cooperative loads
    {
        const float4* src = (const float4*)(oa_buf + (size_t)q0 * 384);
        float4* dst = (float4*)&oa_s[0][0];
        dst[tid] = src[tid];
        if (tid < 128) dst[256 + tid] = src[256 + tid];
        if (tid < 32) ((float*)ref_s)[tid] = refpts[q0 * 8 + tid];
    }
    __syncthreads();

    // phase 2+3 fused: shuffle softmax (16 lanes = one (q,h) group) + tables
    const int HWs[4]    = {100, 50, 25, 13};
    const int starts[4] = {0, 10000, 12500, 13125};
#pragma unroll
    for (int it = 0; it < 2; it++) {
        int s  = tid + it * 256;                 // 0..511
        int i  = s & 15;                         // l*4+p
        int h  = (s >> 4) & 7;
        int ql = s >> 7;
        int l  = i >> 2, p = i & 3;
        float logit = oa_s[ql][256 + h * 16 + i];
        float m = logit;
#pragma unroll
        for (int off = 1; off < 16; off <<= 1) m = fmaxf(m, __shfl_xor(m, off, 64));
        float e = __expf(logit - m);
        float sum = e;
#pragma unroll
        for (int off = 1; off < 16; off <<= 1) sum += __shfl_xor(sum, off, 64);
        float a = e / sum;

        int Wl = HWs[l];
        float fW = (float)Wl;
        float rx = ref_s[ql][l * 2], ry = ref_s[ql][l * 2 + 1];
        float offx = oa_s[ql][h * 32 + l * 8 + p * 2];
        float offy = oa_s[ql][h * 32 + l * 8 + p * 2 + 1];
        float x = rx * fW + offx - 0.5f;
        float y = ry * fW + offy - 0.5f;
        float xf = floorf(x), yf = floorf(y);
        float fx = x - xf, fy = y - yf;
        int x0 = (int)xf, y0 = (int)yf;
        int x1 = x0 + 1, y1 = y0 + 1;
        float wx0 = (x0 >= 0 && x0 < Wl) ? (1.f - fx) : 0.f;
        float wx1 = (x1 >= 0 && x1 < Wl) ? fx : 0.f;
        float wy0 = (y0 >= 0 && y0 < Wl) ? (1.f - fy) : 0.f;
        float wy1 = (y1 >= 0 && y1 < Wl) ? fy : 0.f;
        int x0c = min(max(x0, 0), Wl - 1), x1c = min(max(x1, 0), Wl - 1);
        int y0c = min(max(y0, 0), Wl - 1), y1c = min(max(y1, 0), Wl - 1);
        int r0 = starts[l] + y0c * Wl, r1 = starts[l] + y1c * Wl;

        // physical x-row pair (xb, xb+1) + remapped weights
        int xb = min(max(x0, 0), Wl - 2);
        float wlo = ((x0c == xb)     ? wx0 : 0.f) + ((x1c == xb)     ? wx1 : 0.f);
        float whi = ((x0c == xb + 1) ? wx0 : 0.f) + ((x1c == xb + 1) ? wx1 : 0.f);

        int ti = i * 33 + ql * 8 + h;
        wtab[ti] = make_float4(wy0 * a, wy1 * a, wlo, whi);
        itab[ti] = make_int2(r0 + xb, r1 + xb);
    }
    __syncthreads();

    // phase 4: gather + weighted accumulate; thread = (h, xc, 8-ch group)
    const int dg4 = tid & 3, xc = (tid >> 2) & 1, h = (tid >> 3) & 7, ql = tid >> 6;
    const int q = q0 + ql;
    const int b = q / NQ;
    const char* base = (const char*)v_buf + ((size_t)(b * 8 + h)) * NV * 64 + dg4 * 16;
    const int tbase = ql * 8 + h;

    float a0 = 0.f, a1 = 0.f, a2 = 0.f, a3 = 0.f;
    float a4 = 0.f, a5 = 0.f, a6 = 0.f, a7 = 0.f;
#pragma unroll
    for (int lp = 0; lp < 16; lp++) {
        float4 wv = wtab[lp * 33 + tbase];
        int2   iv = itab[lp * 33 + tbase];
        uint4 s0 = *(const uint4*)(base + ((unsigned)(iv.x + xc) << 6));
        uint4 s1 = *(const uint4*)(base + ((unsigned)(iv.y + xc) << 6));
        float wx = xc ? wv.w : wv.z;
        float w0 = wx * wv.x, w1 = wx * wv.y;
        a0 += w0 * bf2f_lo(s0.x); a1 += w0 * bf2f_hi(s0.x);
        a2 += w0 * bf2f_lo(s0.y); a3 += w0 * bf2f_hi(s0.y);
        a4 += w0 * bf2f_lo(s0.z); a5 += w0 * bf2f_hi(s0.z);
        a6 += w0 * bf2f_lo(s0.w); a7 += w0 * bf2f_hi(s0.w);
        a0 += w1 * bf2f_lo(s1.x); a1 += w1 * bf2f_hi(s1.x);
        a2 += w1 * bf2f_lo(s1.y); a3 += w1 * bf2f_hi(s1.y);
        a4 += w1 * bf2f_lo(s1.z); a5 += w1 * bf2f_hi(s1.z);
        a6 += w1 * bf2f_lo(s1.w); a7 += w1 * bf2f_hi(s1.w);
    }
    // fold the x-corner split (lanes differ in bit 2)
    a0 += __shfl_xor(a0, 4, 64); a1 += __shfl_xor(a1, 4, 64);
    a2 += __shfl_xor(a2, 4, 64); a3 += __shfl_xor(a3, 4, 64);
    a4 += __shfl_xor(a4, 4, 64); a5 += __shfl_xor(a5, 4, 64);
    a6 += __shfl_xor(a6, 4, 64); a7 += __shfl_xor(a7, 4, 64);
    if (xc == 0) {
        uint4 o;
        o.x = (unsigned)f2bf(a0) | ((unsigned)f2bf(a1) << 16);
        o.y = (unsigned)f2bf(a2) | ((unsigned)f2bf(a3) << 16);
        o.z = (unsigned)f2bf(a4) | ((unsigned)f2bf(a5) << 16);
        o.w = (unsigned)f2bf(a6) | ((unsigned)f2bf(a7) << 16);
        *(uint4*)(t_out + (size_t)q * 256 + h * 32 + dg4 * 8) = o;
    }
}

extern "C" void kernel_launch(void* const* d_in, const int* in_sizes, int n_in,
                              void* d_out, int out_size, void* d_ws, size_t ws_size,
                              hipStream_t stream) {
    const float* query  = (const float*)d_in[0];
    const float* value  = (const float*)d_in[1];
    const float* refpts = (const float*)d_in[2];
    // d_in[3] = spatial_shapes (int32) — fixed {100,50,25,13}^2, hard-coded.
    const float* W_off  = (const float*)d_in[4];
    const float* b_off  = (const float*)d_in[5];
    const float* W_attn = (const float*)d_in[6];
    const float* b_attn = (const float*)d_in[7];
    const float* W_val  = (const float*)d_in[8];
    const float* b_val  = (const float*)d_in[9];
    const float* W_out  = (const float*)d_in[10];
    const float* b_out  = (const float*)d_in[11];

    char* wsp = (char*)d_ws;
    size_t o = 0;
    auto carve = [&](size_t bytes) -> void* {
        void* p = wsp + o; o += (bytes + 255) & ~(size_t)255; return p;
    };
    unsigned short* Wt_val = (unsigned short*)carve(256 * 256 * 2);
    unsigned short* Wt_out = (unsigned short*)carve(256 * 256 * 2);
    unsigned short* Wt_qa  = (unsigned short*)carve(384 * 256 * 2);
    float*          b_qa   = (float*)carve(384 * 4);
    unsigned short* v_buf  = (unsigned short*)carve((size_t)BS * NH * NV * 32 * 2);
    float*          oa_buf = (float*)carve((size_t)BS * NQ * 384 * 4);
    unsigned short* t_buf  = (unsigned short*)carve((size_t)BS * NQ * EMBED * 2);

    msda_prep_k<<<896, 256, 0, stream>>>(W_val, W_out, W_off, W_attn,
                                         b_off, b_attn, Wt_val, Wt_out, Wt_qa, b_qa);

    // merged: 832 value blocks + 375 qa blocks; 512 thr, 3x16KB LDS -> 3 blk/CU
    msda_gemm_vq_k<<<832 + 375, 512, 49152, stream>>>(value, query, Wt_val, Wt_qa,
                                                      b_val, b_qa, v_buf, oa_buf);
    // sampler reads oa_buf + v_buf([b][h][pix][32]), writes t_buf
    msda_sampler_k<<<(BS * NQ) / 4, 256, 0, stream>>>(refpts, oa_buf, v_buf, t_buf);
    // out GEMM: 125 m-tiles x 2 n-tiles, reg-staged bf16 A
    msda_gemm_out_k<<<250, 512, 49152, stream>>>(t_buf, Wt_out, b_out, (float*)d_out);
}